// Round 1
// baseline (7176.345 us; speedup 1.0000x reference)
//
#include <hip/hip_runtime.h>

// FlowProjectionModule: forward-warp flow splatting + count-normalize + hole fill.
// B=16, C=2, H=720, W=1280, fp32 in/out.

static constexpr int Bn = 16;
static constexpr int Hn = 720;
static constexpr int Wn = 1280;
static constexpr int HW = Hn * Wn;
static constexpr long long TOT = (long long)Bn * HW;   // 14,745,600

__global__ __launch_bounds__(256) void scatter_k(const float* __restrict__ flow,
                                                 float* __restrict__ out,
                                                 float* __restrict__ cnt) {
    long long i = (long long)blockIdx.x * blockDim.x + threadIdx.x;
    if (i >= TOT) return;
    int b = (int)(i / HW);
    int p = (int)(i - (long long)b * HW);
    int y = p / Wn;
    int x = p - y * Wn;

    const float* f = flow + (size_t)b * 2 * HW;
    float fx = f[p];
    float fy = f[p + HW];

    float x2 = (float)x + fx;
    float y2 = (float)y + fy;
    // valid = in-bounds target; invalid pixels contribute weight-0 adds == no-ops.
    if (!(x2 >= 0.f && y2 >= 0.f && x2 <= (float)(Wn - 1) && y2 <= (float)(Hn - 1)))
        return;

    int xL = (int)floorf(x2); xL = max(0, min(xL, Wn - 1));
    int yT = (int)floorf(y2); yT = max(0, min(yT, Hn - 1));
    int xR = min(xL + 1, Wn - 1);
    int yB = min(yT + 1, Hn - 1);

    float* ox = out + (size_t)b * 2 * HW;
    float* oy = ox + HW;
    float* ct = cnt + (size_t)b * HW;

    int c0 = yT * Wn + xL;
    int c1 = yT * Wn + xR;   // may equal c0 at right border -> double add (matches ref)
    int c2 = yB * Wn + xL;
    int c3 = yB * Wn + xR;

    float nfx = -fx, nfy = -fy;
    atomicAdd(ox + c0, nfx); atomicAdd(oy + c0, nfy); atomicAdd(ct + c0, 1.0f);
    atomicAdd(ox + c1, nfx); atomicAdd(oy + c1, nfy); atomicAdd(ct + c1, 1.0f);
    atomicAdd(ox + c2, nfx); atomicAdd(oy + c2, nfy); atomicAdd(ct + c2, 1.0f);
    atomicAdd(ox + c3, nfx); atomicAdd(oy + c3, nfy); atomicAdd(ct + c3, 1.0f);
}

__global__ __launch_bounds__(256) void norm_k(float* __restrict__ out,
                                              const float* __restrict__ cnt) {
    long long i = (long long)blockIdx.x * blockDim.x + threadIdx.x;
    if (i >= TOT) return;
    int b = (int)(i / HW);
    int p = (int)(i - (long long)b * HW);
    float c = cnt[i];
    float* ox = out + (size_t)b * 2 * HW;
    if (c > 0.f) {
        ox[p]      = ox[p] / c;
        ox[p + HW] = ox[p + HW] / c;
    } else {
        ox[p]      = 0.f;
        ox[p + HW] = 0.f;
    }
}

__global__ __launch_bounds__(256) void fill_k(float* __restrict__ out,
                                              const float* __restrict__ cnt) {
    long long i = (long long)blockIdx.x * blockDim.x + threadIdx.x;
    if (i >= TOT) return;
    int b = (int)(i / HW);
    int p = (int)(i - (long long)b * HW);
    int y = p / Wn;
    int x = p - y * Wn;

    const float* ct = cnt + (size_t)b * HW;
    if (ct[p] > 0.f) return;   // not a hole: normalized value already final

    float* ox = out + (size_t)b * 2 * HW;

    float sx = 0.f, sy = 0.f, num = 0.f;

    // nearest valid to the LEFT in this row
    for (int xx = x - 1; xx >= 0; --xx) {
        int q = y * Wn + xx;
        if (ct[q] > 0.f) { sx += ox[q]; sy += ox[q + HW]; num += 1.f; break; }
    }
    // nearest valid to the RIGHT
    for (int xx = x + 1; xx < Wn; ++xx) {
        int q = y * Wn + xx;
        if (ct[q] > 0.f) { sx += ox[q]; sy += ox[q + HW]; num += 1.f; break; }
    }
    // nearest valid UP in this column
    for (int yy = y - 1; yy >= 0; --yy) {
        int q = yy * Wn + x;
        if (ct[q] > 0.f) { sx += ox[q]; sy += ox[q + HW]; num += 1.f; break; }
    }
    // nearest valid DOWN
    for (int yy = y + 1; yy < Hn; ++yy) {
        int q = yy * Wn + x;
        if (ct[q] > 0.f) { sx += ox[q]; sy += ox[q + HW]; num += 1.f; break; }
    }

    if (num > 0.f) {
        ox[p]      = sx / num;
        ox[p + HW] = sy / num;
    }
    // num==0: stays 0 (norm_k wrote 0), matching reference.
}

extern "C" void kernel_launch(void* const* d_in, const int* in_sizes, int n_in,
                              void* d_out, int out_size, void* d_ws, size_t ws_size,
                              hipStream_t stream) {
    const float* flow = (const float*)d_in[0];
    float* out = (float*)d_out;
    float* cnt = (float*)d_ws;   // B*H*W floats = 59 MB

    size_t out_bytes = (size_t)TOT * 2 * sizeof(float);
    size_t cnt_bytes = (size_t)TOT * sizeof(float);
    hipMemsetAsync(d_out, 0, out_bytes, stream);
    hipMemsetAsync(d_ws, 0, cnt_bytes, stream);

    const int threads = 256;
    const int blocks = (int)((TOT + threads - 1) / threads);   // 57600

    scatter_k<<<blocks, threads, 0, stream>>>(flow, out, cnt);
    norm_k<<<blocks, threads, 0, stream>>>(out, cnt);
    fill_k<<<blocks, threads, 0, stream>>>(out, cnt);
}

// Round 2
// 1345.878 us; speedup vs baseline: 5.3321x; 5.3321x over previous
//
#include <hip/hip_runtime.h>

// FlowProjectionModule: forward-warp flow splatting + count-normalize + hole fill.
// B=16, C=2, H=720, W=1280, fp32 in/out.
//
// Round 2: replace 177M device-scope global atomics (4.95 GB memory-side write
// traffic, 6.85 ms) with bin-by-(b,targetRow) + LDS strip accumulation:
//   count_k -> scan_k -> emit_k -> accum_k (LDS ds_add + coalesced flush,
//   normalization fused) -> fill_k.

static constexpr int Bn = 16;
static constexpr int Hn = 720;
static constexpr int Wn = 1280;
static constexpr int HW = Hn * Wn;
static constexpr long long TOT = (long long)Bn * HW;   // 14,745,600
static constexpr int NBIN = Bn * Hn;                   // 11520 bins keyed (b, yT)

static constexpr int RG   = 8;              // source rows per binning block
static constexpr int HALO = 64;             // |fy| <= 64 handled in LDS hist; else global fallback
static constexpr int NH   = RG + 2 * HALO;  // 136 local hist bins

static constexpr int S  = 4;                // target rows per accum strip
static constexpr int SW = S * Wn;           // 5120 cells per plane

// ---------------- Pass A1: per-bin counts ----------------
__global__ __launch_bounds__(1024) void count_k(const float* __restrict__ flow,
                                                int* __restrict__ bin_count) {
    __shared__ int hist[NH];
    int b  = blockIdx.x / (Hn / RG);
    int g  = blockIdx.x % (Hn / RG);
    int y0 = g * RG;
    for (int i = threadIdx.x; i < NH; i += blockDim.x) hist[i] = 0;
    __syncthreads();

    const float* f = flow + (size_t)b * 2 * HW;
    for (int i = threadIdx.x; i < RG * Wn; i += blockDim.x) {
        int ry = i / Wn;
        int x  = i - ry * Wn;
        int y  = y0 + ry;
        int p  = y * Wn + x;
        float fx = f[p];
        float fy = f[p + HW];
        float x2 = (float)x + fx;
        float y2 = (float)y + fy;
        if (!(x2 >= 0.f && y2 >= 0.f && x2 <= (float)(Wn - 1) && y2 <= (float)(Hn - 1)))
            continue;
        int yT  = (int)floorf(y2);          // in [0, Hn-1] given valid
        int rel = yT - y0 + HALO;
        if (rel >= 0 && rel < NH) atomicAdd(&hist[rel], 1);
        else                      atomicAdd(&bin_count[b * Hn + yT], 1);  // rare outlier
    }
    __syncthreads();
    for (int i = threadIdx.x; i < NH; i += blockDim.x) {
        int c   = hist[i];
        int row = y0 - HALO + i;
        if (c > 0 && row >= 0 && row < Hn)
            atomicAdd(&bin_count[b * Hn + row], c);
    }
}

// ---------------- Pass A2: exclusive scan of 11520 bins (single block) ----------------
__global__ __launch_bounds__(1024) void scan_k(const int* __restrict__ bin_count,
                                               int* __restrict__ off,
                                               int* __restrict__ cur) {
    __shared__ int s[1024];
    const int PER = (NBIN + 1023) / 1024;   // 12
    int t  = threadIdx.x;
    int lo = t * PER;
    int local[12];
    int sum = 0;
    for (int k = 0; k < PER; ++k) {
        int i = lo + k;
        int v = (i < NBIN) ? bin_count[i] : 0;
        local[k] = v;
        sum += v;
    }
    s[t] = sum;
    __syncthreads();
    for (int d = 1; d < 1024; d <<= 1) {    // inclusive Hillis-Steele
        int v = (t >= d) ? s[t - d] : 0;
        __syncthreads();
        s[t] += v;
        __syncthreads();
    }
    int base = s[t] - sum;                  // exclusive prefix for this thread's chunk
    for (int k = 0; k < PER; ++k) {
        int i = lo + k;
        if (i < NBIN) {
            off[i] = base;
            cur[i] = base;
            base += local[k];
        }
    }
    if (t == 1023) off[NBIN] = s[1023];
}

// ---------------- Pass A3: emit records (source pixel index p) into bin segments ----------------
__global__ __launch_bounds__(1024) void emit_k(const float* __restrict__ flow,
                                               int* __restrict__ cur,
                                               int* __restrict__ records) {
    __shared__ int hist[NH];
    __shared__ int base[NH];
    int b  = blockIdx.x / (Hn / RG);
    int g  = blockIdx.x % (Hn / RG);
    int y0 = g * RG;
    for (int i = threadIdx.x; i < NH; i += blockDim.x) hist[i] = 0;
    __syncthreads();

    const float* f = flow + (size_t)b * 2 * HW;
    // phase 1: local histogram
    for (int i = threadIdx.x; i < RG * Wn; i += blockDim.x) {
        int ry = i / Wn;
        int x  = i - ry * Wn;
        int y  = y0 + ry;
        int p  = y * Wn + x;
        float fx = f[p];
        float fy = f[p + HW];
        float x2 = (float)x + fx;
        float y2 = (float)y + fy;
        if (!(x2 >= 0.f && y2 >= 0.f && x2 <= (float)(Wn - 1) && y2 <= (float)(Hn - 1)))
            continue;
        int yT  = (int)floorf(y2);
        int rel = yT - y0 + HALO;
        if (rel >= 0 && rel < NH) atomicAdd(&hist[rel], 1);
        // outliers handled directly in phase 2
    }
    __syncthreads();
    // reserve global ranges, one atomic per nonzero local bin
    for (int i = threadIdx.x; i < NH; i += blockDim.x) {
        int c   = hist[i];
        int row = y0 - HALO + i;
        base[i] = (c > 0 && row >= 0 && row < Hn) ? atomicAdd(&cur[b * Hn + row], c) : 0;
    }
    __syncthreads();
    for (int i = threadIdx.x; i < NH; i += blockDim.x) hist[i] = 0;  // reuse as local cursor
    __syncthreads();
    // phase 2: write records
    for (int i = threadIdx.x; i < RG * Wn; i += blockDim.x) {
        int ry = i / Wn;
        int x  = i - ry * Wn;
        int y  = y0 + ry;
        int p  = y * Wn + x;
        float fx = f[p];
        float fy = f[p + HW];
        float x2 = (float)x + fx;
        float y2 = (float)y + fy;
        if (!(x2 >= 0.f && y2 >= 0.f && x2 <= (float)(Wn - 1) && y2 <= (float)(Hn - 1)))
            continue;
        int yT  = (int)floorf(y2);
        int rel = yT - y0 + HALO;
        if (rel >= 0 && rel < NH) {
            int slot = atomicAdd(&hist[rel], 1);
            records[base[rel] + slot] = p;
        } else {
            int slot = atomicAdd(&cur[b * Hn + yT], 1);   // rare outlier
            records[slot] = p;
        }
    }
}

// ---------------- Pass B: per-strip LDS accumulation + fused normalize ----------------
__global__ __launch_bounds__(256) void accum_k(const float* __restrict__ flow,
                                               const int* __restrict__ off,
                                               const int* __restrict__ records,
                                               float* __restrict__ out,
                                               float* __restrict__ cnt) {
    __shared__ float acc[3 * SW];           // [ox | oy | cnt] planes, 60 KB
    int b  = blockIdx.x / (Hn / S);
    int st = blockIdx.x % (Hn / S);
    int r0 = st * S;

    for (int i = threadIdx.x; i < 3 * SW; i += blockDim.x) acc[i] = 0.f;
    __syncthreads();

    int rlo = max(r0 - 1, 0);
    int rhi = min(r0 + S - 1, Hn - 1);
    int lo  = off[b * Hn + rlo];
    int hi  = off[b * Hn + rhi + 1];

    const float* f = flow + (size_t)b * 2 * HW;
    for (int j = lo + threadIdx.x; j < hi; j += blockDim.x) {
        int p = records[j];
        int y = p / Wn;
        int x = p - y * Wn;
        float fx = f[p];
        float fy = f[p + HW];
        float x2 = (float)x + fx;
        float y2 = (float)y + fy;
        int xL = (int)floorf(x2);
        int yT = (int)floorf(y2);
        int xR = min(xL + 1, Wn - 1);
        int yB = min(yT + 1, Hn - 1);
        float nfx = -fx, nfy = -fy;
        #pragma unroll
        for (int rr = 0; rr < 2; ++rr) {
            int row = rr ? yB : yT;          // yT==yB at bottom edge -> double add (matches ref)
            if (row >= r0 && row < r0 + S) {
                int rb = (row - r0) * Wn;
                atomicAdd(&acc[rb + xL], nfx);
                atomicAdd(&acc[rb + xR], nfx);          // xL==xR at right edge -> double add
                atomicAdd(&acc[SW + rb + xL], nfy);
                atomicAdd(&acc[SW + rb + xR], nfy);
                atomicAdd(&acc[2 * SW + rb + xL], 1.f);
                atomicAdd(&acc[2 * SW + rb + xR], 1.f);
            }
        }
    }
    __syncthreads();

    float* ox = out + (size_t)b * 2 * HW;
    float* ct = cnt + (size_t)b * HW;
    for (int i = threadIdx.x; i < SW; i += blockDim.x) {
        int rw  = i / Wn;
        int col = i - rw * Wn;
        int p   = (r0 + rw) * Wn + col;
        float c = acc[2 * SW + i];
        float vx = 0.f, vy = 0.f;
        if (c > 0.f) {
            vx = acc[i] / c;
            vy = acc[SW + i] / c;
        }
        ox[p]      = vx;
        ox[p + HW] = vy;
        ct[p]      = c;
    }
}

// ---------------- hole fill (unchanged from round 1, validated) ----------------
__global__ __launch_bounds__(256) void fill_k(float* __restrict__ out,
                                              const float* __restrict__ cnt) {
    long long i = (long long)blockIdx.x * blockDim.x + threadIdx.x;
    if (i >= TOT) return;
    int b = (int)(i / HW);
    int p = (int)(i - (long long)b * HW);
    int y = p / Wn;
    int x = p - y * Wn;

    const float* ct = cnt + (size_t)b * HW;
    if (ct[p] > 0.f) return;   // not a hole

    float* ox = out + (size_t)b * 2 * HW;
    float sx = 0.f, sy = 0.f, num = 0.f;

    for (int xx = x - 1; xx >= 0; --xx) {
        int q = y * Wn + xx;
        if (ct[q] > 0.f) { sx += ox[q]; sy += ox[q + HW]; num += 1.f; break; }
    }
    for (int xx = x + 1; xx < Wn; ++xx) {
        int q = y * Wn + xx;
        if (ct[q] > 0.f) { sx += ox[q]; sy += ox[q + HW]; num += 1.f; break; }
    }
    for (int yy = y - 1; yy >= 0; --yy) {
        int q = yy * Wn + x;
        if (ct[q] > 0.f) { sx += ox[q]; sy += ox[q + HW]; num += 1.f; break; }
    }
    for (int yy = y + 1; yy < Hn; ++yy) {
        int q = yy * Wn + x;
        if (ct[q] > 0.f) { sx += ox[q]; sy += ox[q + HW]; num += 1.f; break; }
    }

    if (num > 0.f) {
        ox[p]      = sx / num;
        ox[p + HW] = sy / num;
    }
}

extern "C" void kernel_launch(void* const* d_in, const int* in_sizes, int n_in,
                              void* d_out, int out_size, void* d_ws, size_t ws_size,
                              hipStream_t stream) {
    const float* flow = (const float*)d_in[0];
    float* out = (float*)d_out;

    // workspace layout (all 256B-aligned):
    //   cnt:       TOT floats            (59.0 MB)
    //   bin_count: NBIN ints
    //   off:       NBIN+1 ints
    //   cur:       NBIN ints
    //   records:   TOT ints              (59.0 MB)
    char* ws = (char*)d_ws;
    size_t o = 0;
    float* cnt = (float*)(ws + o);  o += (size_t)TOT * sizeof(float);
    o = (o + 255) & ~(size_t)255;
    int* bin_count = (int*)(ws + o); o += (size_t)NBIN * sizeof(int);
    o = (o + 255) & ~(size_t)255;
    int* off = (int*)(ws + o);       o += (size_t)(NBIN + 1) * sizeof(int);
    o = (o + 255) & ~(size_t)255;
    int* cur = (int*)(ws + o);       o += (size_t)NBIN * sizeof(int);
    o = (o + 255) & ~(size_t)255;
    int* records = (int*)(ws + o);   o += (size_t)TOT * sizeof(int);

    hipMemsetAsync(bin_count, 0, (size_t)NBIN * sizeof(int), stream);

    const int bin_blocks = Bn * (Hn / RG);   // 1440
    count_k<<<bin_blocks, 1024, 0, stream>>>(flow, bin_count);
    scan_k<<<1, 1024, 0, stream>>>(bin_count, off, cur);
    emit_k<<<bin_blocks, 1024, 0, stream>>>(flow, cur, records);

    const int strip_blocks = Bn * (Hn / S);  // 2880
    accum_k<<<strip_blocks, 256, 0, stream>>>(flow, off, records, out, cnt);

    const int threads = 256;
    const int blocks = (int)((TOT + threads - 1) / threads);
    fill_k<<<blocks, threads, 0, stream>>>(out, cnt);
}